// Round 1
// baseline (1384.363 us; speedup 1.0000x reference)
//
#include <hip/hip_runtime.h>
#include <stdint.h>

#pragma clang fp contract(off)

#define NN 1024
#define BB 2048
#define ENS 1000
#define KK 32
#define CSEG 64
#define NSEG (NN / CSEG)
#define NCKPT (NSEG - 1)

#define NEGC -1.0e9f
#define PADV -1.0e10f

// ===================== XLA:CPU float32 math replicas (variant V1) =====================
// Cephes/Eigen-classic exp with FMA everywhere mul feeds add (FPOpFusion::Fast on CPU).
__device__ __forceinline__ float xla_expf(float xin) {
  float x = fminf(xin, 88.3762626647950f);
  x = fmaxf(x, -88.3762626647949f);
  float fx = floorf(__builtin_fmaf(x, 1.44269504088896341f, 0.5f));
  x = __builtin_fmaf(fx, -0.693359375f, x);      // x -= fx*C1
  x = __builtin_fmaf(fx, 2.12194440e-4f, x);     // x -= fx*C2 (C2 = -2.12194440e-4)
  float z = x * x;
  float y = 1.9875691500e-4f;
  y = __builtin_fmaf(y, x, 1.3981999507e-3f);
  y = __builtin_fmaf(y, x, 8.3334519073e-3f);
  y = __builtin_fmaf(y, x, 4.1665795894e-2f);
  y = __builtin_fmaf(y, x, 1.6666665459e-1f);
  y = __builtin_fmaf(y, x, 5.0000001201e-1f);
  y = __builtin_fmaf(y, z, x);                   // (poly*z + x)
  y = y + 1.0f;                                  // ... + 1
  int n = (int)fx;
  float two_n = __int_as_float((n + 127) << 23); // n in [-127,128]; n=-127 -> +0.0
  return y * two_n;
}

// Cephes/Eigen-classic logf (Horner, FMA).
__device__ __forceinline__ float xla_logf(float uin) {
  int ib = __float_as_int(uin);
  float e = (float)((ib >> 23) - 126);
  float m = __int_as_float((ib & 0x007FFFFF) | 0x3F000000);  // [0.5, 1)
  bool lt = m < 0.707106781186547524f;
  float tmp = lt ? m : 0.0f;
  e = lt ? (e - 1.0f) : e;
  float x = m - 1.0f;
  x = x + tmp;
  float z = x * x;
  float y = 7.0376836292e-2f;
  y = __builtin_fmaf(y, x, -1.1514610310e-1f);
  y = __builtin_fmaf(y, x, 1.1676998740e-1f);
  y = __builtin_fmaf(y, x, -1.2420140846e-1f);
  y = __builtin_fmaf(y, x, 1.4249322787e-1f);
  y = __builtin_fmaf(y, x, -1.6668057665e-1f);
  y = __builtin_fmaf(y, x, 2.0000714765e-1f);
  y = __builtin_fmaf(y, x, -2.4999993993e-1f);
  y = __builtin_fmaf(y, x, 3.3333331174e-1f);
  y = y * x;
  y = y * z;
  y = __builtin_fmaf(e, -2.12194440e-4f, y);     // y += e*q1
  y = __builtin_fmaf(z, -0.5f, y);               // y -= 0.5*z
  x = x + y;
  x = __builtin_fmaf(e, 0.693359375f, x);        // x += e*q2
  return x;
}

// XLA ElementalIrEmitter::EmitLog1p
__device__ __forceinline__ float xla_log1pf(float x) {
  float lg = xla_logf(x + 1.0f);
  float sm = __builtin_fmaf(-0.5f, x, 1.0f) * x;
  return (fabsf(x) < 1e-4f) ? sm : lg;
}

// jnp.logaddexp: max + log1p(exp(-|x1-x2|)); no NaNs occur in this problem.
__device__ __forceinline__ float xla_logaddexp(float a, float b) {
  float amax = fmaxf(a, b);
  float delta = a - b;
  return amax + xla_log1pf(xla_expf(-fabsf(delta)));
}

// logsigmoid(v) = -softplus(-v) + 1e-7 ; softplus(y) = max(y,0)+log1p(exp(-|y|))
__device__ __forceinline__ float xla_logsigmoid(float v) {
  float y = -v;
  float amax = fmaxf(y, 0.0f);
  float sp = amax + xla_log1pf(xla_expf(-fabsf(y)));
  return -sp + 1e-7f;
}

// ===================== JAX threefry2x32, key(42) = (0, 42) =====================
__device__ __forceinline__ uint32_t rotl_(uint32_t v, int s) { return (v << s) | (v >> (32 - s)); }

// partitionable 32-bit path: bits = out0 ^ out1 with counter (hi=0, lo=m)
__device__ __forceinline__ uint32_t threefry_fold(uint32_t x0, uint32_t x1) {
  const uint32_t ks0 = 0u;
  const uint32_t ks1 = 42u;
  const uint32_t ks2 = 0x1BD11BDAu ^ 42u;
  uint32_t v0 = x0 + ks0;
  uint32_t v1 = x1 + ks1;
#define TF_R(rr) { v0 += v1; v1 = rotl_(v1, rr); v1 ^= v0; }
  TF_R(13) TF_R(15) TF_R(26) TF_R(6)
  v0 += ks1; v1 += ks2 + 1u;
  TF_R(17) TF_R(29) TF_R(16) TF_R(24)
  v0 += ks2; v1 += ks0 + 2u;
  TF_R(13) TF_R(15) TF_R(26) TF_R(6)
  v0 += ks0; v1 += ks1 + 3u;
  TF_R(17) TF_R(29) TF_R(16) TF_R(24)
  v0 += ks1; v1 += ks2 + 4u;
  TF_R(13) TF_R(15) TF_R(26) TF_R(6)
  v0 += ks2; v1 += ks0 + 5u;
#undef TF_R
  return v0 ^ v1;
}

__device__ __forceinline__ float jax_uniform01(uint32_t m) {
  uint32_t bits = threefry_fold(0u, m);
  return __uint_as_float((bits >> 9) | 0x3F800000u) - 1.0f;
}

// ===================== esp scan step =====================
// wave = 2 rows x 32 j-lanes (j = g+1, j=0 channel provably absorbs to 0.0f)
__device__ __forceinline__ float s_step(float sOld, float a, int g) {
  float prev = __shfl_up(sOld, 1, 64);
  float sh = (g == 0) ? 0.0f : prev;   // state[j-1]
  float t = a + sh;
  return xla_logaddexp(sOld, t);       // delta = old - t, matching jnp arg order
}

// ===================== kernels =====================
__global__ __launch_bounds__(256) void k_flat(const float* __restrict__ scores,
                                              float* __restrict__ flat) {
  int idx = blockIdx.x * 256 + threadIdx.x;
  if (idx >= BB * NN) return;
  int b = idx >> 10;
  int i = idx & (NN - 1);
  float x = (i < ENS) ? scores[b * ENS + i] : PADV;
  flat[idx] = xla_logsigmoid(x);
}

// Backward suffix-ESP scan; store checkpoints S[c*64] for c=1..15.
__global__ __launch_bounds__(64) void k_sscan(const float* __restrict__ flat,
                                              float* __restrict__ ckpt) {
  int lane = threadIdx.x;
  int half = lane >> 5, g = lane & 31;
  int row = blockIdx.x * 2 + half;
  const float* frow = flat + row * NN;
  float s = NEGC;  // S[N][j>=1] = NEG
  for (int i = NN - 1; i >= 0; --i) {
    s = s_step(s, frow[i], g);
    if ((i & (CSEG - 1)) == 0 && i > 0) {
      int c = (i >> 6) - 1;  // 0..14
      ckpt[(c * BB + row) * 33 + (g + 1)] = s;
    }
  }
}

// Forward pass: per segment recompute S into LDS; run F-scan, marginals lse, exact sampler.
__global__ __launch_bounds__(64) void k_main(const float* __restrict__ flat,
                                             const float* __restrict__ ckpt,
                                             float* __restrict__ logZ,
                                             float* __restrict__ outbuf) {
  __shared__ float Sseg[2][CSEG + 1][33];
  int lane = threadIdx.x;
  int half = lane >> 5, g = lane & 31;
  int row = blockIdx.x * 2 + half;
  const float* frow = flat + row * NN;

  float F = NEGC;  // F[0][j>=1]
  int r = KK;      // lane-uniform per half

  for (int seg = 0; seg < NSEG; ++seg) {
    int base = seg * CSEG;
    float s = (seg == NSEG - 1) ? NEGC : ckpt[(seg * BB + row) * 33 + (g + 1)];
    __syncthreads();
    Sseg[half][CSEG][g + 1] = s;
    if (g == 0) Sseg[half][CSEG][0] = 0.0f;
    for (int t = CSEG - 1; t >= 0; --t) {
      s = s_step(s, frow[base + t], g);
      Sseg[half][t][g + 1] = s;
      if (g == 0) Sseg[half][t][0] = 0.0f;
    }
    __syncthreads();

    for (int tt = 0; tt < CSEG; ++tt) {
      int i = base + tt;
      float a = frow[i];

      // ---- marginals (tolerant path): pair[g] = F[g] + S[i+1][31-g] ----
      float Fp = __shfl_up(F, 1, 64);
      float Fj = (g == 0) ? 0.0f : Fp;  // F[i][j-1] == F[i][g]
      float pairv = Fj + Sseg[half][tt + 1][31 - g];
      float mx = pairv;
      #pragma unroll
      for (int d = 16; d >= 1; d >>= 1) mx = fmaxf(mx, __shfl_xor(mx, d, 64));
      float ex = xla_expf(pairv - mx);
      float sm = ex;
      #pragma unroll
      for (int d = 16; d >= 1; d >>= 1) sm += __shfl_xor(sm, d, 64);
      float lsev = xla_logf(sm) + mx;
      if (g == 0 && i < ENS) outbuf[BB * ENS + row * ENS + i] = a + lsev;

      // ---- exact sampler ----
      int rc = r < 1 ? 1 : (r > KK ? KK : r);
      float s1 = Sseg[half][tt + 1][rc - 1];
      float s2 = Sseg[half][tt][rc];
      float val = (a + s1) - s2;
      float p = xla_expf(val);
      p = fminf(fmaxf(p, 0.0f), 1.0f);
      if (r <= 0) p = 0.0f;
      float u = jax_uniform01((uint32_t)(i * BB + row));
      int inc = (u < p) ? 1 : 0;
      r -= inc;
      if (g == 0 && i < ENS) outbuf[row * ENS + i] = (float)inc;

      // ---- F update ----
      float tF = a + Fj;
      F = xla_logaddexp(F, tF);
    }
  }
  if (g == 31) logZ[row] = F;  // F[N][32]
}

__global__ __launch_bounds__(256) void k_final(const float* __restrict__ logZ,
                                               float* __restrict__ outbuf) {
  int idx = blockIdx.x * 256 + threadIdx.x;
  if (idx >= BB * ENS) return;
  int b = idx / ENS;
  float lsev = outbuf[BB * ENS + idx];
  float marg = xla_expf(lsev - logZ[b]);
  float bit = outbuf[idx];
  outbuf[idx] = (bit - marg) + marg;   // straight-through value
  outbuf[BB * ENS + idx] = marg;
}

extern "C" void kernel_launch(void* const* d_in, const int* in_sizes, int n_in,
                              void* d_out, int out_size, void* d_ws, size_t ws_size,
                              hipStream_t stream) {
  const float* scores = (const float*)d_in[0];
  float* outbuf = (float*)d_out;
  float* ws = (float*)d_ws;
  float* flat = ws;                               // BB*NN
  float* ckpt = ws + (size_t)BB * NN;             // NCKPT*BB*33
  float* logZ = ckpt + (size_t)NCKPT * BB * 33;   // BB
  (void)in_sizes; (void)n_in; (void)out_size; (void)ws_size;

  hipLaunchKernelGGL(k_flat, dim3((BB * NN + 255) / 256), dim3(256), 0, stream, scores, flat);
  hipLaunchKernelGGL(k_sscan, dim3(BB / 2), dim3(64), 0, stream, flat, ckpt);
  hipLaunchKernelGGL(k_main, dim3(BB / 2), dim3(64), 0, stream, flat, ckpt, logZ, outbuf);
  hipLaunchKernelGGL(k_final, dim3((BB * ENS + 255) / 256), dim3(256), 0, stream, logZ, outbuf);
}

// Round 4
// 646.782 us; speedup vs baseline: 2.1404x; 2.1404x over previous
//
#include <hip/hip_runtime.h>
#include <stdint.h>

#pragma clang fp contract(off)

#define NN 1024
#define BB 2048
#define ENS 1000
#define KK 32

#define NEGC -1.0e9f
#define PADV -1.0e10f

// ===================== XLA:CPU float32 math replicas (exact path) =====================
__device__ __forceinline__ float xla_expf(float xin) {
  float x = fminf(xin, 88.3762626647950f);
  x = fmaxf(x, -88.3762626647949f);
  float fx = floorf(__builtin_fmaf(x, 1.44269504088896341f, 0.5f));
  x = __builtin_fmaf(fx, -0.693359375f, x);
  x = __builtin_fmaf(fx, 2.12194440e-4f, x);
  float z = x * x;
  float y = 1.9875691500e-4f;
  y = __builtin_fmaf(y, x, 1.3981999507e-3f);
  y = __builtin_fmaf(y, x, 8.3334519073e-3f);
  y = __builtin_fmaf(y, x, 4.1665795894e-2f);
  y = __builtin_fmaf(y, x, 1.6666665459e-1f);
  y = __builtin_fmaf(y, x, 5.0000001201e-1f);
  y = __builtin_fmaf(y, z, x);
  y = y + 1.0f;
  int n = (int)fx;
  float two_n = __int_as_float((n + 127) << 23);
  return y * two_n;
}

__device__ __forceinline__ float xla_logf(float uin) {
  int ib = __float_as_int(uin);
  float e = (float)((ib >> 23) - 126);
  float m = __int_as_float((ib & 0x007FFFFF) | 0x3F000000);
  bool lt = m < 0.707106781186547524f;
  float tmp = lt ? m : 0.0f;
  e = lt ? (e - 1.0f) : e;
  float x = m - 1.0f;
  x = x + tmp;
  float z = x * x;
  float y = 7.0376836292e-2f;
  y = __builtin_fmaf(y, x, -1.1514610310e-1f);
  y = __builtin_fmaf(y, x, 1.1676998740e-1f);
  y = __builtin_fmaf(y, x, -1.2420140846e-1f);
  y = __builtin_fmaf(y, x, 1.4249322787e-1f);
  y = __builtin_fmaf(y, x, -1.6668057665e-1f);
  y = __builtin_fmaf(y, x, 2.0000714765e-1f);
  y = __builtin_fmaf(y, x, -2.4999993993e-1f);
  y = __builtin_fmaf(y, x, 3.3333331174e-1f);
  y = y * x;
  y = y * z;
  y = __builtin_fmaf(e, -2.12194440e-4f, y);
  y = __builtin_fmaf(z, -0.5f, y);
  x = x + y;
  x = __builtin_fmaf(e, 0.693359375f, x);
  return x;
}

__device__ __forceinline__ float xla_log1pf(float x) {
  float lg = xla_logf(x + 1.0f);
  float sm = __builtin_fmaf(-0.5f, x, 1.0f) * x;
  return (fabsf(x) < 1e-4f) ? sm : lg;
}

__device__ __forceinline__ float xla_logsigmoid(float v) {
  float y = -v;
  float amax = fmaxf(y, 0.0f);
  float sp = amax + xla_log1pf(xla_expf(-fabsf(y)));
  return -sp + 1e-7f;
}

// ===================== fast math (marginal path only; 2e-2 tolerance) ==============
__device__ __forceinline__ float fexp2(float x) { return __builtin_amdgcn_exp2f(x); }
__device__ __forceinline__ float flog2(float x) { return __builtin_amdgcn_logf(x); }

__device__ __forceinline__ float fast_lae(float a, float b) {
  float m = fmaxf(a, b);
  float d = -fabsf(a - b);
  float e = fexp2(d * 1.44269504088896341f);
  return m + flog2(1.0f + e) * 0.69314718055994531f;
}

// ===================== JAX threefry2x32, key(42) =====================
__device__ __forceinline__ uint32_t rotl_(uint32_t v, int s) { return (v << s) | (v >> (32 - s)); }

__device__ __forceinline__ uint32_t threefry_fold(uint32_t x0, uint32_t x1) {
  const uint32_t ks0 = 0u;
  const uint32_t ks1 = 42u;
  const uint32_t ks2 = 0x1BD11BDAu ^ 42u;
  uint32_t v0 = x0 + ks0;
  uint32_t v1 = x1 + ks1;
#define TF_R(rr) { v0 += v1; v1 = rotl_(v1, rr); v1 ^= v0; }
  TF_R(13) TF_R(15) TF_R(26) TF_R(6)
  v0 += ks1; v1 += ks2 + 1u;
  TF_R(17) TF_R(29) TF_R(16) TF_R(24)
  v0 += ks2; v1 += ks0 + 2u;
  TF_R(13) TF_R(15) TF_R(26) TF_R(6)
  v0 += ks0; v1 += ks1 + 3u;
  TF_R(17) TF_R(29) TF_R(16) TF_R(24)
  v0 += ks1; v1 += ks2 + 4u;
  TF_R(13) TF_R(15) TF_R(26) TF_R(6)
  v0 += ks2; v1 += ks0 + 5u;
#undef TF_R
  return v0 ^ v1;
}

__device__ __forceinline__ float jax_uniform01(uint32_t m) {
  uint32_t bits = threefry_fold(0u, m);
  return __uint_as_float((bits >> 9) | 0x3F800000u) - 1.0f;
}

// ===================== kernels =====================

// flat = logsigmoid(padded scores) [exact]; U = threefry uniforms, layout [row][i]
__global__ __launch_bounds__(256) void k_flat(const float* __restrict__ scores,
                                              float* __restrict__ flat,
                                              float* __restrict__ U) {
  int idx = blockIdx.x * 256 + threadIdx.x;
  if (idx >= BB * NN) return;
  int row = idx >> 10;
  int i = idx & (NN - 1);
  float x = (i < ENS) ? scores[row * ENS + i] : PADV;
  flat[idx] = xla_logsigmoid(x);
  U[idx] = jax_uniform01((uint32_t)(i * BB + row));
}

// Pass 1: S-wave = exact backward suffix-ESP scan -> ckpt[seg]=S[(seg+1)*64].
//         F-wave = fast forward ESP scan -> fckpt[seg]=F[(seg+1)*64], logZ.
__global__ __launch_bounds__(128) void k_scan1(const float* __restrict__ flat,
                                               float* __restrict__ ckpt,
                                               float* __restrict__ fckpt,
                                               float* __restrict__ logZ) {
  int w = threadIdx.x >> 6;
  int lane = threadIdx.x & 63;
  int g = lane & 31, half = lane >> 5;
  int row = blockIdx.x * 2 + half;
  int role = (w + blockIdx.x) & 1;
  const float* frow = flat + (size_t)row * NN;

  if (role == 0) {
    float s = NEGC;  // S[N][j>=1]
    for (int seg = 15; seg >= 0; --seg) {
      if (seg <= 14) ckpt[((size_t)seg * BB + row) * 32 + g] = s;  // S[(seg+1)*64]
      float awA = frow[seg * 64 + g];
      float awB = frow[seg * 64 + 32 + g];
      #pragma unroll 8
      for (int t = 63; t >= 0; --t) {
        float a = __shfl((t & 32) ? awB : awA, (lane & 32) + (t & 31), 64);
        float prev = __shfl_up(s, 1, 64);
        float sh = (g == 0) ? 0.0f : prev;
        float tv = a + sh;
        float amax = fmaxf(s, tv);
        float delta = s - tv;
        s = amax + xla_log1pf(xla_expf(-fabsf(delta)));
      }
    }
  } else {
    float F = NEGC;  // F[0][j>=1]
    for (int seg = 0; seg <= 15; ++seg) {
      float awA = frow[seg * 64 + g];
      float awB = frow[seg * 64 + 32 + g];
      #pragma unroll 8
      for (int t = 0; t < 64; ++t) {
        float a = __shfl((t & 32) ? awB : awA, (lane & 32) + (t & 31), 64);
        float prev = __shfl_up(F, 1, 64);
        float Fj = (g == 0) ? 0.0f : prev;
        F = fast_lae(F, a + Fj);
      }
      if (seg <= 14) fckpt[((size_t)seg * BB + row) * 32 + g] = F;  // F[(seg+1)*64]
    }
    if (g == 31) logZ[row] = F;  // logZ = F[N][32]
  }
}

// Pass 2 (FORWARD segments): producer recomputes seg=ph exactly from ckpt,
// emitting pv[item][ch] into a 2-deep LDS ring; consumer samples seg=ph-1
// threading the serial r-chain in the correct i=0..N-1 order.
__global__ __launch_bounds__(128) void k_fused(const float* __restrict__ flat,
                                               const float* __restrict__ U,
                                               const float* __restrict__ ckpt,
                                               uint32_t* __restrict__ bits) {
  __shared__ float pbuf[2][2][64][32];   // [ring][half][item][ch] 32 KiB
  int w = threadIdx.x >> 6;
  int lane = threadIdx.x & 63;
  int g = lane & 31, half = lane >> 5;
  int row = blockIdx.x * 2 + half;
  int role = (w + blockIdx.x) & 1;
  const float* frow = flat + (size_t)row * NN;

  if (role == 0) {
    // ---- producer: exact per-segment recompute (backward within segment) ----
    for (int ph = 0; ph <= 16; ++ph) {
      if (ph <= 15) {
        int seg = ph;
        float s = (seg == 15) ? NEGC : ckpt[((size_t)seg * BB + row) * 32 + g];
        float awA = frow[seg * 64 + g];
        float awB = frow[seg * 64 + 32 + g];
        float* pb = &pbuf[ph & 1][half][0][0];
        #pragma unroll 8
        for (int t = 63; t >= 0; --t) {
          float a = __shfl((t & 32) ? awB : awA, (lane & 32) + (t & 31), 64);
          float prev = __shfl_up(s, 1, 64);
          float sh = (g == 0) ? 0.0f : prev;      // S[i+1][g]  (s1 for rc=g+1)
          float tv = a + sh;                      // (a + s1)
          float amax = fmaxf(s, tv);
          float delta = s - tv;
          float snew = amax + xla_log1pf(xla_expf(-fabsf(delta)));  // S[i][g+1] (s2)
          float pv = xla_expf(tv - snew);         // exp((a+s1)-s2)
          pv = fminf(fmaxf(pv, 0.0f), 1.0f);      // clip(p,0,1)
          pb[t * 32 + g] = pv;
          s = snew;
        }
      }
      __syncthreads();
    }
  } else {
    // ---- consumer: serial sampler, forward segments, one phase behind ----
    int r = KK;
    float uwA = U[(size_t)row * NN + g];          // stage seg 0 uniforms
    float uwB = U[(size_t)row * NN + 32 + g];
    for (int ph = 0; ph <= 16; ++ph) {
      if (ph >= 1) {
        int seg = ph - 1;
        const float* pb = &pbuf[(ph - 1) & 1][half][0][0];
        uint32_t word = 0;
        #pragma unroll
        for (int tt = 0; tt < 64; ++tt) {
          int rc = r < 1 ? 1 : (r > KK ? KK : r);
          float pv = pb[tt * 32 + (rc - 1)];
          float u = __shfl((tt & 32) ? uwB : uwA, (lane & 32) + (tt & 31), 64);
          int inc = (r > 0) && (u < pv);
          r -= inc;
          word |= ((uint32_t)inc) << (tt & 31);
          if ((tt & 31) == 31) {
            if (g == 0) bits[row * 32 + seg * 2 + (tt >> 5)] = word;
            word = 0;
          }
        }
        int sn = ph;  // stage uniforms for next phase's segment
        if (sn <= 15) {
          uwA = U[(size_t)row * NN + sn * 64 + g];
          uwB = U[(size_t)row * NN + sn * 64 + 32 + g];
        }
      }
      __syncthreads();
    }
  }
}

// Marginals: fully parallel over (row-pair, segment). Fast math throughout.
__global__ __launch_bounds__(64) void k_marg(const float* __restrict__ flat,
                                             const float* __restrict__ ckpt,
                                             const float* __restrict__ fckpt,
                                             float* __restrict__ lsebuf) {
  __shared__ float Sseg[2][65][33];
  int lane = threadIdx.x;
  int g = lane & 31;
  int half = lane >> 5;
  int rp = blockIdx.x >> 4;
  int seg = blockIdx.x & 15;
  int row = rp * 2 + half;
  const float* frow = flat + (size_t)row * NN;
  int base = seg * 64;

  float awA = frow[base + g];
  float awB = frow[base + 32 + g];

  float s = (seg == 15) ? NEGC : ckpt[((size_t)seg * BB + row) * 32 + g];
  Sseg[half][64][g + 1] = s;
  if (g == 0) Sseg[half][64][0] = 0.0f;
  #pragma unroll 8
  for (int t = 63; t >= 0; --t) {
    float a = __shfl((t & 32) ? awB : awA, (lane & 32) + (t & 31), 64);
    float prev = __shfl_up(s, 1, 64);
    float sh = (g == 0) ? 0.0f : prev;
    s = fast_lae(s, a + sh);
    Sseg[half][t][g + 1] = s;
    if (g == 0) Sseg[half][t][0] = 0.0f;
  }
  __syncthreads();

  float F = (seg == 0) ? NEGC : fckpt[((size_t)(seg - 1) * BB + row) * 32 + g];
  #pragma unroll 4
  for (int tt = 0; tt < 64; ++tt) {
    int i = base + tt;
    float a = __shfl((tt & 32) ? awB : awA, (lane & 32) + (tt & 31), 64);
    float prev = __shfl_up(F, 1, 64);
    float Fj = (g == 0) ? 0.0f : prev;
    float pairv = Fj + Sseg[half][tt + 1][31 - g];
    float mx = pairv;
    #pragma unroll
    for (int d = 16; d >= 1; d >>= 1) mx = fmaxf(mx, __shfl_xor(mx, d, 64));
    float ex = fexp2((pairv - mx) * 1.44269504088896341f);
    float sm = ex;
    #pragma unroll
    for (int d = 16; d >= 1; d >>= 1) sm += __shfl_xor(sm, d, 64);
    float lsev = flog2(sm) * 0.69314718055994531f + mx;
    if (g == 0 && i < ENS) lsebuf[(size_t)row * ENS + i] = a + lsev;
    F = fast_lae(F, a + Fj);
  }
}

// Combine: marg = exp(lse - logZ); samples = (bit - marg) + marg
__global__ __launch_bounds__(256) void k_final(const float* __restrict__ lsebuf,
                                               const float* __restrict__ logZ,
                                               const uint32_t* __restrict__ bits,
                                               float* __restrict__ out) {
  int idx = blockIdx.x * 256 + threadIdx.x;
  if (idx >= BB * ENS) return;
  int row = idx / ENS;
  int i = idx - row * ENS;
  float lz = logZ[row];
  float marg = fexp2((lsebuf[idx] - lz) * 1.44269504088896341f);
  uint32_t wbits = bits[row * 32 + (i >> 5)];
  float bit = (float)((wbits >> (i & 31)) & 1u);
  out[idx] = (bit - marg) + marg;
  out[(size_t)BB * ENS + idx] = marg;
}

extern "C" void kernel_launch(void* const* d_in, const int* in_sizes, int n_in,
                              void* d_out, int out_size, void* d_ws, size_t ws_size,
                              hipStream_t stream) {
  const float* scores = (const float*)d_in[0];
  float* outbuf = (float*)d_out;
  float* lsebuf = outbuf + (size_t)BB * ENS;      // stage lse in upper half of d_out

  float* ws = (float*)d_ws;
  float* flat = ws;                                // BB*NN
  float* U = flat + (size_t)BB * NN;               // BB*NN
  float* ckpt = U + (size_t)BB * NN;               // 15*BB*32
  float* fckpt = ckpt + (size_t)15 * BB * 32;      // 15*BB*32
  float* logZ = fckpt + (size_t)15 * BB * 32;      // BB
  uint32_t* bits = (uint32_t*)(logZ + BB);         // BB*32 words
  (void)in_sizes; (void)n_in; (void)out_size; (void)ws_size;

  hipLaunchKernelGGL(k_flat, dim3((BB * NN + 255) / 256), dim3(256), 0, stream,
                     scores, flat, U);
  hipLaunchKernelGGL(k_scan1, dim3(BB / 2), dim3(128), 0, stream,
                     flat, ckpt, fckpt, logZ);
  hipLaunchKernelGGL(k_fused, dim3(BB / 2), dim3(128), 0, stream,
                     flat, U, ckpt, bits);
  hipLaunchKernelGGL(k_marg, dim3((BB / 2) * 16), dim3(64), 0, stream,
                     flat, ckpt, fckpt, lsebuf);
  hipLaunchKernelGGL(k_final, dim3((BB * ENS + 255) / 256), dim3(256), 0, stream,
                     lsebuf, logZ, bits, outbuf);
}

// Round 5
// 627.328 us; speedup vs baseline: 2.2068x; 1.0310x over previous
//
#include <hip/hip_runtime.h>
#include <stdint.h>

#pragma clang fp contract(off)

#define NN 1024
#define BB 2048
#define ENS 1000
#define KK 32

#define NEGC -1.0e9f
#define PADV -1.0e10f
#define L2E 1.44269504088896341f

// ===================== XLA:CPU float32 math replicas (exact path) =====================
__device__ __forceinline__ float xla_expf(float xin) {
  float x = fminf(xin, 88.3762626647950f);
  x = fmaxf(x, -88.3762626647949f);
  float fx = floorf(__builtin_fmaf(x, 1.44269504088896341f, 0.5f));
  x = __builtin_fmaf(fx, -0.693359375f, x);
  x = __builtin_fmaf(fx, 2.12194440e-4f, x);
  float z = x * x;
  float y = 1.9875691500e-4f;
  y = __builtin_fmaf(y, x, 1.3981999507e-3f);
  y = __builtin_fmaf(y, x, 8.3334519073e-3f);
  y = __builtin_fmaf(y, x, 4.1665795894e-2f);
  y = __builtin_fmaf(y, x, 1.6666665459e-1f);
  y = __builtin_fmaf(y, x, 5.0000001201e-1f);
  y = __builtin_fmaf(y, z, x);
  y = y + 1.0f;
  int n = (int)fx;
  float two_n = __int_as_float((n + 127) << 23);
  return y * two_n;
}

__device__ __forceinline__ float xla_logf(float uin) {
  int ib = __float_as_int(uin);
  float e = (float)((ib >> 23) - 126);
  float m = __int_as_float((ib & 0x007FFFFF) | 0x3F000000);
  bool lt = m < 0.707106781186547524f;
  float tmp = lt ? m : 0.0f;
  e = lt ? (e - 1.0f) : e;
  float x = m - 1.0f;
  x = x + tmp;
  float z = x * x;
  float y = 7.0376836292e-2f;
  y = __builtin_fmaf(y, x, -1.1514610310e-1f);
  y = __builtin_fmaf(y, x, 1.1676998740e-1f);
  y = __builtin_fmaf(y, x, -1.2420140846e-1f);
  y = __builtin_fmaf(y, x, 1.4249322787e-1f);
  y = __builtin_fmaf(y, x, -1.6668057665e-1f);
  y = __builtin_fmaf(y, x, 2.0000714765e-1f);
  y = __builtin_fmaf(y, x, -2.4999993993e-1f);
  y = __builtin_fmaf(y, x, 3.3333331174e-1f);
  y = y * x;
  y = y * z;
  y = __builtin_fmaf(e, -2.12194440e-4f, y);
  y = __builtin_fmaf(z, -0.5f, y);
  x = x + y;
  x = __builtin_fmaf(e, 0.693359375f, x);
  return x;
}

__device__ __forceinline__ float xla_log1pf(float x) {
  float lg = xla_logf(x + 1.0f);
  float sm = __builtin_fmaf(-0.5f, x, 1.0f) * x;
  return (fabsf(x) < 1e-4f) ? sm : lg;
}

__device__ __forceinline__ float xla_logsigmoid(float v) {
  float y = -v;
  float amax = fmaxf(y, 0.0f);
  float sp = amax + xla_log1pf(xla_expf(-fabsf(y)));
  return -sp + 1e-7f;
}

// ===================== fast math (marginal path only; 2e-2 tolerance) ==============
__device__ __forceinline__ float fexp2(float x) { return __builtin_amdgcn_exp2f(x); }
__device__ __forceinline__ float flog2(float x) { return __builtin_amdgcn_logf(x); }

__device__ __forceinline__ float fast_lae(float a, float b) {
  float m = fmaxf(a, b);
  float d = -fabsf(a - b);
  float e = fexp2(d * L2E);
  return m + flog2(1.0f + e) * 0.69314718055994531f;
}

// ===================== DPP cross-lane helpers (VALU pipe, not LDS) =====================
#if __has_builtin(__builtin_amdgcn_update_dpp)
#define HAVE_DPP 1
#endif

template <int CTRL>
__device__ __forceinline__ float dppmov(float x) {
#ifdef HAVE_DPP
  return __int_as_float(__builtin_amdgcn_update_dpp(0, __float_as_int(x), CTRL, 0xF, 0xF, false));
#else
  return x;
#endif
}

// shift-up-by-1 across the wave (lane i <- lane i-1); lanes 0/32 fixed by caller's cndmask
__device__ __forceinline__ float shup1(float x) {
#ifdef HAVE_DPP
  return dppmov<0x138>(x);   // wave_shr:1
#else
  return __shfl_up(x, 1, 64);
#endif
}

// sum over the 32 lanes of each half (result in all lanes of the half)
__device__ __forceinline__ float sum32(float x) {
#ifdef HAVE_DPP
  x += dppmov<0x128>(x);     // row_ror:8
  x += dppmov<0x124>(x);     // row_ror:4
  x += dppmov<0x122>(x);     // row_ror:2
  x += dppmov<0x121>(x);     // row_ror:1
  x += __shfl_xor(x, 16, 64);
#else
  #pragma unroll
  for (int d = 16; d >= 1; d >>= 1) x += __shfl_xor(x, d, 64);
#endif
  return x;
}

// ===================== JAX threefry2x32, key(42) =====================
__device__ __forceinline__ uint32_t rotl_(uint32_t v, int s) { return (v << s) | (v >> (32 - s)); }

__device__ __forceinline__ uint32_t threefry_fold(uint32_t x0, uint32_t x1) {
  const uint32_t ks0 = 0u;
  const uint32_t ks1 = 42u;
  const uint32_t ks2 = 0x1BD11BDAu ^ 42u;
  uint32_t v0 = x0 + ks0;
  uint32_t v1 = x1 + ks1;
#define TF_R(rr) { v0 += v1; v1 = rotl_(v1, rr); v1 ^= v0; }
  TF_R(13) TF_R(15) TF_R(26) TF_R(6)
  v0 += ks1; v1 += ks2 + 1u;
  TF_R(17) TF_R(29) TF_R(16) TF_R(24)
  v0 += ks2; v1 += ks0 + 2u;
  TF_R(13) TF_R(15) TF_R(26) TF_R(6)
  v0 += ks0; v1 += ks1 + 3u;
  TF_R(17) TF_R(29) TF_R(16) TF_R(24)
  v0 += ks1; v1 += ks2 + 4u;
  TF_R(13) TF_R(15) TF_R(26) TF_R(6)
  v0 += ks2; v1 += ks0 + 5u;
#undef TF_R
  return v0 ^ v1;
}

__device__ __forceinline__ float jax_uniform01(uint32_t m) {
  uint32_t bits = threefry_fold(0u, m);
  return __uint_as_float((bits >> 9) | 0x3F800000u) - 1.0f;
}

// exact logsigmoid of padded score, computed inline (no flat buffer)
__device__ __forceinline__ float load_a(const float* __restrict__ srow, int i) {
  float x = (i < ENS) ? srow[i] : PADV;
  return xla_logsigmoid(x);
}

// ===================== mega kernel =====================
// block = 3 waves, 2 rows. wave roles (rotated by blockIdx):
//  role 0: phase A exact backward S-scan (ckpt in reg shift-stack) -> phase B exact
//          producer (recompute seg forward order, full S values into LDS ring)
//  role 1: phase A fast F-scan (logZ in reg) -> phase B marginal wave (no-max LSE
//          centered on logZ, DPP rotate-reduce, writes marg directly)
//  role 2: phase B serial top-k sampler (inline threefry), one phase behind producer
__global__ __launch_bounds__(192) void k_mega(const float* __restrict__ scores,
                                              float* __restrict__ margOut,
                                              uint32_t* __restrict__ bits) {
  __shared__ float Sring[2][2][65][32];   // [slot][half][item(+boundary)][ch-1] 33280 B
  int w = threadIdx.x >> 6;
  int lane = threadIdx.x & 63;
  int g = lane & 31, half = lane >> 5;
  int row = blockIdx.x * 2 + half;
  const float* srow = scores + (size_t)row * ENS;
  int role = (w + blockIdx.x) % 3;

  if (role == 0) {
    // ---------- phase A: exact backward S-scan ----------
    float ck[15];
    float s = NEGC;
    for (int seg = 15; seg >= 0; --seg) {
      if (seg <= 14) {           // push S[(seg+1)*64] (LIFO; popped forward)
        #pragma unroll
        for (int q = 14; q >= 1; --q) ck[q] = ck[q - 1];
        ck[0] = s;
      }
      float awA = load_a(srow, seg * 64 + g);
      float awB = load_a(srow, seg * 64 + 32 + g);
      #pragma unroll 8
      for (int t = 63; t >= 0; --t) {
        float a = __shfl((t & 32) ? awB : awA, (lane & 32) + (t & 31), 64);
        float prev = shup1(s);
        float sh = (g == 0) ? 0.0f : prev;
        float tv = a + sh;
        float amax = fmaxf(s, tv);
        s = amax + xla_log1pf(xla_expf(-fabsf(s - tv)));
      }
    }
    __syncthreads();
    // ---------- phase B: exact producer ----------
    for (int ph = 0; ph <= 16; ++ph) {
      if (ph <= 15) {
        int seg = ph;
        float st;
        if (seg == 15) st = NEGC;
        else {
          st = ck[0];
          #pragma unroll
          for (int q = 0; q <= 13; ++q) ck[q] = ck[q + 1];
        }
        float awA = load_a(srow, seg * 64 + g);
        float awB = load_a(srow, seg * 64 + 32 + g);
        float* ring = &Sring[ph & 1][half][0][0];
        ring[64 * 32 + g] = st;             // boundary S[(seg+1)*64]
        float s = st;
        #pragma unroll 8
        for (int t = 63; t >= 0; --t) {
          float a = __shfl((t & 32) ? awB : awA, (lane & 32) + (t & 31), 64);
          float prev = shup1(s);
          float sh = (g == 0) ? 0.0f : prev;
          float tv = a + sh;
          float amax = fmaxf(s, tv);
          s = amax + xla_log1pf(xla_expf(-fabsf(s - tv)));
          ring[t * 32 + g] = s;             // S[seg*64+t][g+1]
        }
      }
      __syncthreads();
    }
  } else if (role == 1) {
    // ---------- phase A: fast F-scan -> logZ ----------
    float F = NEGC;
    for (int seg = 0; seg <= 15; ++seg) {
      float awA = load_a(srow, seg * 64 + g);
      float awB = load_a(srow, seg * 64 + 32 + g);
      #pragma unroll 8
      for (int t = 0; t < 64; ++t) {
        float a = __shfl((t & 32) ? awB : awA, (lane & 32) + (t & 31), 64);
        float prev = shup1(F);
        float Fj = (g == 0) ? 0.0f : prev;
        F = fast_lae(F, a + Fj);
      }
    }
    float lz = __shfl(F, (lane & 32) + 31, 64);   // logZ = F[N][32]
    __syncthreads();
    // ---------- phase B: marginal wave (no-max LSE: pair <= logZ always) ----------
    float F2 = NEGC;
    for (int ph = 0; ph <= 16; ++ph) {
      if (ph >= 1) {
        int seg = ph - 1;
        const float* ring = &Sring[(ph - 1) & 1][half][0][0];
        float awA = load_a(srow, seg * 64 + g);
        float awB = load_a(srow, seg * 64 + 32 + g);
        #pragma unroll 4
        for (int tt = 0; tt < 64; ++tt) {
          int i = seg * 64 + tt;
          float a = __shfl((tt & 32) ? awB : awA, (lane & 32) + (tt & 31), 64);
          float prev = shup1(F2);
          float Fj = (g == 0) ? 0.0f : prev;
          float sv = 0.0f;                               // S[i+1][0] = 0 for g==31
          if (g != 31) sv = ring[(tt + 1) * 32 + (30 - g)];
          float pairv = Fj + sv;                         // F[i][g] + S[i+1][31-g]
          float term = fexp2((pairv - lz) * L2E);        // <= 1, no overflow
          float sm = sum32(term);
          if (g == 0 && i < ENS)
            margOut[(size_t)row * ENS + i] = fexp2(a * L2E) * sm;
          F2 = fast_lae(F2, a + Fj);
        }
      }
      __syncthreads();
    }
  } else {
    // ---------- consumer: exact serial top-k sampler ----------
    __syncthreads();
    int r = KK;
    for (int ph = 0; ph <= 16; ++ph) {
      if (ph >= 1) {
        int seg = ph - 1;
        const float* ring = &Sring[(ph - 1) & 1][half][0][0];
        float awA = load_a(srow, seg * 64 + g);
        float awB = load_a(srow, seg * 64 + 32 + g);
        float uwA = jax_uniform01((uint32_t)((seg * 64 + g) * BB + row));
        float uwB = jax_uniform01((uint32_t)((seg * 64 + 32 + g) * BB + row));
        uint32_t word = 0;
        #pragma unroll
        for (int tt = 0; tt < 64; ++tt) {
          int rc = r < 1 ? 1 : (r > KK ? KK : r);
          float s1 = (rc == 1) ? 0.0f : ring[(tt + 1) * 32 + (rc - 2)];  // S[i+1][rc-1]
          float s2 = ring[tt * 32 + (rc - 1)];                           // S[i][rc]
          float a = __shfl((tt & 32) ? awB : awA, (lane & 32) + (tt & 31), 64);
          float u = __shfl((tt & 32) ? uwB : uwA, (lane & 32) + (tt & 31), 64);
          float val = (a + s1) - s2;
          float p = xla_expf(val);
          p = fminf(fmaxf(p, 0.0f), 1.0f);
          int inc = (r > 0) && (u < p);
          r -= inc;
          word |= ((uint32_t)inc) << (tt & 31);
          if ((tt & 31) == 31) {
            if (g == 0) bits[row * 32 + seg * 2 + (tt >> 5)] = word;
            word = 0;
          }
        }
      }
      __syncthreads();
    }
  }
}

// samples = (bit - marg) + marg ; marg already final in margOut (= out upper half)
__global__ __launch_bounds__(256) void k_final(const float* __restrict__ margOut,
                                               const uint32_t* __restrict__ bits,
                                               float* __restrict__ out) {
  int idx = blockIdx.x * 256 + threadIdx.x;
  if (idx >= BB * ENS) return;
  int row = idx / ENS;
  int i = idx - row * ENS;
  float marg = margOut[idx];
  uint32_t wbits = bits[row * 32 + (i >> 5)];
  float bit = (float)((wbits >> (i & 31)) & 1u);
  out[idx] = (bit - marg) + marg;
}

extern "C" void kernel_launch(void* const* d_in, const int* in_sizes, int n_in,
                              void* d_out, int out_size, void* d_ws, size_t ws_size,
                              hipStream_t stream) {
  const float* scores = (const float*)d_in[0];
  float* outbuf = (float*)d_out;
  float* margOut = outbuf + (size_t)BB * ENS;   // marginals live in out's upper half
  uint32_t* bits = (uint32_t*)d_ws;             // BB*32 words
  (void)in_sizes; (void)n_in; (void)out_size; (void)ws_size;

  hipLaunchKernelGGL(k_mega, dim3(BB / 2), dim3(192), 0, stream,
                     scores, margOut, bits);
  hipLaunchKernelGGL(k_final, dim3((BB * ENS + 255) / 256), dim3(256), 0, stream,
                     margOut, bits, outbuf);
}

// Round 6
// 480.552 us; speedup vs baseline: 2.8808x; 1.3054x over previous
//
#include <hip/hip_runtime.h>
#include <stdint.h>

#pragma clang fp contract(off)

#define NN 1024
#define BB 2048
#define ENS 1000
#define KK 32

#define NEGC -1.0e9f
#define PADV -1.0e10f
#define L2E 1.44269504088896341f

// ===================== XLA:CPU float32 math replicas (exact path) =====================
__device__ __forceinline__ float xla_expf(float xin) {
  float x = fminf(xin, 88.3762626647950f);
  x = fmaxf(x, -88.3762626647949f);
  float fx = floorf(__builtin_fmaf(x, 1.44269504088896341f, 0.5f));
  x = __builtin_fmaf(fx, -0.693359375f, x);
  x = __builtin_fmaf(fx, 2.12194440e-4f, x);
  float z = x * x;
  float y = 1.9875691500e-4f;
  y = __builtin_fmaf(y, x, 1.3981999507e-3f);
  y = __builtin_fmaf(y, x, 8.3334519073e-3f);
  y = __builtin_fmaf(y, x, 4.1665795894e-2f);
  y = __builtin_fmaf(y, x, 1.6666665459e-1f);
  y = __builtin_fmaf(y, x, 5.0000001201e-1f);
  y = __builtin_fmaf(y, z, x);
  y = y + 1.0f;
  int n = (int)fx;
  float two_n = __int_as_float((n + 127) << 23);
  return y * two_n;
}

__device__ __forceinline__ float xla_logf(float uin) {
  int ib = __float_as_int(uin);
  float e = (float)((ib >> 23) - 126);
  float m = __int_as_float((ib & 0x007FFFFF) | 0x3F000000);
  bool lt = m < 0.707106781186547524f;
  float tmp = lt ? m : 0.0f;
  e = lt ? (e - 1.0f) : e;
  float x = m - 1.0f;
  x = x + tmp;
  float z = x * x;
  float y = 7.0376836292e-2f;
  y = __builtin_fmaf(y, x, -1.1514610310e-1f);
  y = __builtin_fmaf(y, x, 1.1676998740e-1f);
  y = __builtin_fmaf(y, x, -1.2420140846e-1f);
  y = __builtin_fmaf(y, x, 1.4249322787e-1f);
  y = __builtin_fmaf(y, x, -1.6668057665e-1f);
  y = __builtin_fmaf(y, x, 2.0000714765e-1f);
  y = __builtin_fmaf(y, x, -2.4999993993e-1f);
  y = __builtin_fmaf(y, x, 3.3333331174e-1f);
  y = y * x;
  y = y * z;
  y = __builtin_fmaf(e, -2.12194440e-4f, y);
  y = __builtin_fmaf(z, -0.5f, y);
  x = x + y;
  x = __builtin_fmaf(e, 0.693359375f, x);
  return x;
}

__device__ __forceinline__ float xla_log1pf(float x) {
  float lg = xla_logf(x + 1.0f);
  float sm = __builtin_fmaf(-0.5f, x, 1.0f) * x;
  return (fabsf(x) < 1e-4f) ? sm : lg;
}

__device__ __forceinline__ float xla_logsigmoid(float v) {
  float y = -v;
  float amax = fmaxf(y, 0.0f);
  float sp = amax + xla_log1pf(xla_expf(-fabsf(y)));
  return -sp + 1e-7f;
}

// ===================== fast math (marginal path only; 2e-2 tolerance) ==============
__device__ __forceinline__ float fexp2(float x) { return __builtin_amdgcn_exp2f(x); }
__device__ __forceinline__ float flog2(float x) { return __builtin_amdgcn_logf(x); }

__device__ __forceinline__ float fast_lae(float a, float b) {
  float m = fmaxf(a, b);
  float d = -fabsf(a - b);
  float e = fexp2(d * L2E);
  return m + flog2(1.0f + e) * 0.69314718055994531f;
}

// ===================== DPP cross-lane helpers (VALU pipe, zero LDS traffic) ========
template <int CTRL, int ROWM>
__device__ __forceinline__ float dppz(float x) {
  // old = 0: masked/out-of-row lanes yield 0
  return __int_as_float(__builtin_amdgcn_update_dpp(0, __float_as_int(x), CTRL, ROWM, 0xF, false));
}

// lane i <- lane i-1 (lanes 0/32 handled by caller's g==0 select)
__device__ __forceinline__ float shup1(float x) { return dppz<0x138, 0xF>(x); }  // wave_shr:1

// per-half (32-lane) sum; total lands in lanes 31 and 63 (g==31 of each half)
__device__ __forceinline__ float sum_half_last(float x) {
  x += dppz<0x111, 0xF>(x);   // row_shr:1
  x += dppz<0x112, 0xF>(x);   // row_shr:2
  x += dppz<0x114, 0xF>(x);   // row_shr:4
  x += dppz<0x118, 0xF>(x);   // row_shr:8  -> lane15/31/47/63 hold row totals
  x += dppz<0x142, 0xA>(x);   // row_bcast15, rows 1&3 only (no cross-half leak)
  return x;
}

// ===================== JAX threefry2x32, key(42) =====================
__device__ __forceinline__ uint32_t rotl_(uint32_t v, int s) { return (v << s) | (v >> (32 - s)); }

__device__ __forceinline__ uint32_t threefry_fold(uint32_t x0, uint32_t x1) {
  const uint32_t ks0 = 0u;
  const uint32_t ks1 = 42u;
  const uint32_t ks2 = 0x1BD11BDAu ^ 42u;
  uint32_t v0 = x0 + ks0;
  uint32_t v1 = x1 + ks1;
#define TF_R(rr) { v0 += v1; v1 = rotl_(v1, rr); v1 ^= v0; }
  TF_R(13) TF_R(15) TF_R(26) TF_R(6)
  v0 += ks1; v1 += ks2 + 1u;
  TF_R(17) TF_R(29) TF_R(16) TF_R(24)
  v0 += ks2; v1 += ks0 + 2u;
  TF_R(13) TF_R(15) TF_R(26) TF_R(6)
  v0 += ks0; v1 += ks1 + 3u;
  TF_R(17) TF_R(29) TF_R(16) TF_R(24)
  v0 += ks1; v1 += ks2 + 4u;
  TF_R(13) TF_R(15) TF_R(26) TF_R(6)
  v0 += ks2; v1 += ks0 + 5u;
#undef TF_R
  return v0 ^ v1;
}

__device__ __forceinline__ float jax_uniform01(uint32_t m) {
  uint32_t bits = threefry_fold(0u, m);
  return __uint_as_float((bits >> 9) | 0x3F800000u) - 1.0f;
}

// exact logsigmoid of padded score (bit-identical wherever computed)
__device__ __forceinline__ float load_a(const float* __restrict__ srow, int i) {
  float x = (i < ENS) ? srow[i] : PADV;
  return xla_logsigmoid(x);
}

// ===================== kernel 1: checkpoints + logZ =====================
// block = 2 waves x 2 rows. role0: exact backward S-scan -> ckpt[seg]=S[(seg+1)*64].
// role1: fast forward F-scan -> logZ. No barriers. a staged via LDS broadcast.
__global__ __launch_bounds__(128) void k_scan1(const float* __restrict__ scores,
                                               float* __restrict__ ckpt,
                                               float* __restrict__ logZ) {
  __shared__ float abuf[2][2][64];   // [wave][half][item]
  int w = threadIdx.x >> 6;
  int lane = threadIdx.x & 63;
  int g = lane & 31, half = lane >> 5;
  int row = blockIdx.x * 2 + half;
  const float* srow = scores + (size_t)row * ENS;
  int role = (w + blockIdx.x) & 1;
  float* la = &abuf[w][half][0];

  if (role == 0) {
    float s = NEGC;
    for (int seg = 15; seg >= 0; --seg) {
      if (seg <= 14) ckpt[((size_t)seg * BB + row) * 32 + g] = s;
      la[g] = load_a(srow, seg * 64 + g);
      la[32 + g] = load_a(srow, seg * 64 + 32 + g);
      __builtin_amdgcn_s_waitcnt(0);   // lgkmcnt(0): LDS writes visible to own wave
      #pragma unroll 8
      for (int t = 63; t >= 0; --t) {
        float a = la[t];
        float prev = shup1(s);
        float sh = (g == 0) ? 0.0f : prev;
        float tv = a + sh;
        float amax = fmaxf(s, tv);
        s = amax + xla_log1pf(xla_expf(-fabsf(s - tv)));
      }
    }
  } else {
    float F = NEGC;
    for (int seg = 0; seg <= 15; ++seg) {
      la[g] = load_a(srow, seg * 64 + g);
      la[32 + g] = load_a(srow, seg * 64 + 32 + g);
      __builtin_amdgcn_s_waitcnt(0);
      #pragma unroll 8
      for (int t = 0; t < 64; ++t) {
        float a = la[t];
        float prev = shup1(F);
        float Fj = (g == 0) ? 0.0f : prev;
        F = fast_lae(F, a + Fj);
      }
    }
    if (g == 31) logZ[row] = F;   // F[N][32]
  }
}

// ===================== kernel 2: producer + sampler + marginals =====================
// block = 3 waves x 2 rows, roles rotated by blockIdx%3.
//  producer: exact forward-order segment recompute from ckpt -> raw S ring
//  consumer: exact serial top-k sampler (1 phase behind), inline threefry
//  marg:     no-max LSE centered on logZ, DPP reduce, in-register F chain
__global__ __launch_bounds__(192) void k_fusedB(const float* __restrict__ scores,
                                                const float* __restrict__ ckpt,
                                                const float* __restrict__ logZ,
                                                float* __restrict__ margOut,
                                                uint32_t* __restrict__ bits) {
  __shared__ float ring[2][2][65][32];   // raw S values, 33280 B
  __shared__ float abuf[2][2][64];       // staged a, 1024 B
  __shared__ float ubuf[2][64];          // staged u (consumer private), 512 B
  int w = threadIdx.x >> 6;
  int lane = threadIdx.x & 63;
  int g = lane & 31, half = lane >> 5;
  int row = blockIdx.x * 2 + half;
  const float* srow = scores + (size_t)row * ENS;
  int role = (w + blockIdx.x) % 3;

  if (role == 0) {
    // ---------- producer ----------
    for (int ph = 0; ph <= 16; ++ph) {
      if (ph <= 15) {
        int seg = ph;
        float s = (seg == 15) ? NEGC : ckpt[((size_t)seg * BB + row) * 32 + g];
        float* la = &abuf[ph & 1][half][0];
        float* rg = &ring[ph & 1][half][0][0];
        la[g] = load_a(srow, seg * 64 + g);
        la[32 + g] = load_a(srow, seg * 64 + 32 + g);
        rg[64 * 32 + g] = s;                   // boundary S[(seg+1)*64]
        __builtin_amdgcn_s_waitcnt(0);
        #pragma unroll 8
        for (int t = 63; t >= 0; --t) {
          float a = la[t];
          float prev = shup1(s);
          float sh = (g == 0) ? 0.0f : prev;
          float tv = a + sh;
          float amax = fmaxf(s, tv);
          s = amax + xla_log1pf(xla_expf(-fabsf(s - tv)));
          rg[t * 32 + g] = s;                  // S[seg*64+t][g+1]
        }
      }
      __syncthreads();
    }
  } else if (role == 1) {
    // ---------- consumer: exact serial top-k sampler ----------
    int r = KK;
    for (int ph = 0; ph <= 16; ++ph) {
      if (ph >= 1) {
        int seg = ph - 1;
        const float* rg = &ring[(ph - 1) & 1][half][0][0];
        const float* la = &abuf[(ph - 1) & 1][half][0];
        float* lu = &ubuf[half][0];
        lu[g] = jax_uniform01((uint32_t)((seg * 64 + g) * BB + row));
        lu[32 + g] = jax_uniform01((uint32_t)((seg * 64 + 32 + g) * BB + row));
        __builtin_amdgcn_s_waitcnt(0);
        uint32_t word = 0;
        #pragma unroll 8
        for (int t = 0; t < 64; ++t) {
          int rc = r < 1 ? 1 : (r > KK ? KK : r);
          int c1 = rc - 2 < 0 ? 0 : rc - 2;
          float s2 = rg[t * 32 + (rc - 1)];
          float s1r = rg[(t + 1) * 32 + c1];
          float s1 = (rc == 1) ? 0.0f : s1r;
          float a = la[t];
          float u = lu[t];
          float p = xla_expf((a + s1) - s2);
          p = fminf(fmaxf(p, 0.0f), 1.0f);
          int inc = (r > 0) && (u < p);
          r -= inc;
          word |= ((uint32_t)inc) << (t & 31);
          if ((t & 31) == 31) {
            if (g == 0) bits[row * 32 + seg * 2 + (t >> 5)] = word;
            word = 0;
          }
        }
      }
      __syncthreads();
    }
  } else {
    // ---------- marg: no-max LSE centered on logZ ----------
    float F = NEGC;
    float lz = logZ[row];
    for (int ph = 0; ph <= 16; ++ph) {
      if (ph >= 1) {
        int seg = ph - 1;
        const float* rg = &ring[(ph - 1) & 1][half][0][0];
        const float* la = &abuf[(ph - 1) & 1][half][0];
        #pragma unroll 4
        for (int t = 0; t < 64; ++t) {
          int i = seg * 64 + t;
          float a = la[t];
          float prev = shup1(F);
          float Fj = (g == 0) ? 0.0f : prev;
          float sv = (g == 31) ? 0.0f : rg[(t + 1) * 32 + (30 - g)];
          float term = fexp2((Fj + sv - lz) * L2E);   // pair <= logZ -> term <= ~1
          float tot = sum_half_last(term);            // total at g==31
          if (g == 31 && i < ENS)
            margOut[(size_t)row * ENS + i] = fexp2(a * L2E) * tot;
          F = fast_lae(F, a + Fj);
        }
      }
      __syncthreads();
    }
  }
}

// samples = (bit - marg) + marg ; marg already final in margOut (= out upper half)
__global__ __launch_bounds__(256) void k_final(const float* __restrict__ margOut,
                                               const uint32_t* __restrict__ bits,
                                               float* __restrict__ out) {
  int idx = blockIdx.x * 256 + threadIdx.x;
  if (idx >= BB * ENS) return;
  int row = idx / ENS;
  int i = idx - row * ENS;
  float marg = margOut[idx];
  uint32_t wbits = bits[row * 32 + (i >> 5)];
  float bit = (float)((wbits >> (i & 31)) & 1u);
  out[idx] = (bit - marg) + marg;
}

extern "C" void kernel_launch(void* const* d_in, const int* in_sizes, int n_in,
                              void* d_out, int out_size, void* d_ws, size_t ws_size,
                              hipStream_t stream) {
  const float* scores = (const float*)d_in[0];
  float* outbuf = (float*)d_out;
  float* margOut = outbuf + (size_t)BB * ENS;   // marginals live in out's upper half

  float* ws = (float*)d_ws;
  float* ckpt = ws;                              // 15*BB*32
  float* logZ = ckpt + (size_t)15 * BB * 32;     // BB
  uint32_t* bits = (uint32_t*)(logZ + BB);       // BB*32 words
  (void)in_sizes; (void)n_in; (void)out_size; (void)ws_size;

  hipLaunchKernelGGL(k_scan1, dim3(BB / 2), dim3(128), 0, stream,
                     scores, ckpt, logZ);
  hipLaunchKernelGGL(k_fusedB, dim3(BB / 2), dim3(192), 0, stream,
                     scores, ckpt, logZ, margOut, bits);
  hipLaunchKernelGGL(k_final, dim3((BB * ENS + 255) / 256), dim3(256), 0, stream,
                     margOut, bits, outbuf);
}